// Round 2
// baseline (365.577 us; speedup 1.0000x reference)
//
#include <hip/hip_runtime.h>
#include <hip/hip_bf16.h>

// SupPixPool: out[b,c,k] = max over pixels p with spx[b,p]==k of img[b,c,p].
// B=4, C=64, H=W=512, K=1024.
//
// Round-7: ELIMINATE LDS ATOMICS. R6's read-filter was neutral -> ds_max cost
// is ~190-200 cyc per wave-instruction regardless of exec mask; 1.05M atomic
// wave-instrs alone price out at ~325 us of the 353 us. New structure:
//   - each WAVE owns one channel and a PRIVATE 1024-word LDS table (16 waves
//     x 4KB = 64KB/block), so no cross-wave races exist;
//   - updates are plain ds_write guarded by a read-filter, with a
//     write -> readback -> retry loop to resolve same-address collisions
//     among lanes of the same (lock-step) wave instruction. Table values are
//     always genuinely-observed encodings and only grow, so convergence to
//     the true max is guaranteed; no atomics anywhere in the hot loop.
// Grid: (b, cgroup-of-16, chunk-of-8192-pixels) = 4*4*32 = 512 blocks.
// spx chunk (32KB) is re-read by all 16 waves of a block -> L1-resident.

constexpr int Kseg = 1024;
constexpr int Bn   = 4;
constexpr int Cn   = 64;
constexpr int HWn  = 512 * 512;

constexpr int TPB    = 1024;
constexpr int WAVES  = TPB / 64;           // 16 waves = 16 channels per block
constexpr int NCGRP  = Cn / WAVES;         // 4 channel groups
constexpr int NCHUNK = 32;                 // pixel chunks per (b, cgrp)
constexpr int PIX    = HWn / NCHUNK;       // 8192 pixels per block
constexpr int NBLK   = Bn * NCGRP * NCHUNK;   // 512
constexpr int ITERS  = PIX / (64 * 4);        // 32 vf4 iters per wave
constexpr int TBLW   = WAVES * Kseg;          // 16384 words = 64KB LDS

typedef float  vf4 __attribute__((ext_vector_type(4)));
typedef int    vi4 __attribute__((ext_vector_type(4)));

// order-preserving float->uint encoding: enc monotonic, unsigned max == fmax
constexpr unsigned ENEG = 0x007FFFFFu;  // enc(-inf)

__device__ __forceinline__ unsigned enc(float f) {
    unsigned u = __float_as_uint(f);
    return u ^ ((unsigned)((int)u >> 31) | 0x80000000u);
}
__device__ __forceinline__ float dec(unsigned e) {
    unsigned u = (e & 0x80000000u) ? (e ^ 0x80000000u) : ~e;
    return __uint_as_float(u);
}

// Wave-private max update: plain write + readback-verify. Safe ONLY because
// wt is private to this wave (all racers are lock-step lanes of one instr).
// Table monotonicity: every write is a real observed encoding; after round 1
// each subsequent write exceeds the last-read table value, so values never
// regress and the loop terminates in <= duplicate-multiplicity rounds.
__device__ __forceinline__ void wave_max4(unsigned* wt,
                                          int kx, int ky, int kz, int kw,
                                          unsigned ex, unsigned ey,
                                          unsigned ez, unsigned ew) {
    unsigned cx = wt[kx], cy = wt[ky], cz = wt[kz], cw = wt[kw];
    bool bx = ex > cx, by = ey > cy, bz = ez > cz, bw = ew > cw;
    while (__any(bx | by | bz | bw)) {
        if (bx) wt[kx] = ex;
        if (by) wt[ky] = ey;
        if (bz) wt[kz] = ez;
        if (bw) wt[kw] = ew;
        if (bx) bx = ex > wt[kx];
        if (by) by = ey > wt[ky];
        if (bz) bz = ez > wt[kz];
        if (bw) bw = ew > wt[kw];
    }
}

__global__ __launch_bounds__(TPB, 8) void pool_partial(
    const float* __restrict__ img, const int* __restrict__ spx,
    unsigned* __restrict__ part) {
    __shared__ unsigned tbl[TBLW];  // 64KB: 16 wave-private 1024-word tables

    const int bx    = blockIdx.x;
    const int chunk = bx % NCHUNK;
    const int cg    = (bx / NCHUNK) % NCGRP;
    const int b     = bx / (NCHUNK * NCGRP);

    for (int i = threadIdx.x; i < TBLW; i += TPB) tbl[i] = ENEG;
    __syncthreads();

    const int w    = threadIdx.x >> 6;   // wave id = channel-in-group 0..15
    const int lane = threadIdx.x & 63;
    unsigned* wt = tbl + w * Kseg;       // this wave's private table

    const int c = cg * WAVES + w;
    const float* imgc = img + ((size_t)(b * Cn + c)) * HWn
                            + (size_t)chunk * PIX;
    const int*   spxb = spx + (size_t)b * HWn + (size_t)chunk * PIX;

    // depth-1 pipeline: loads for it+1 issued before LDS work of it
    vf4 v = __builtin_nontemporal_load((const vf4*)(imgc + 4 * lane));
    vi4 k = *(const vi4*)(spxb + 4 * lane);

#pragma unroll 4
    for (int it = 0; it < ITERS; ++it) {
        vf4 vn;
        vi4 kn;
        if (it + 1 < ITERS) {
            const int qn = lane + (it + 1) * 64;
            vn = __builtin_nontemporal_load((const vf4*)(imgc + 4 * qn));
            kn = *(const vi4*)(spxb + 4 * qn);
        }
        const int kx = k.x & (Kseg - 1);
        const int ky = k.y & (Kseg - 1);
        const int kz = k.z & (Kseg - 1);
        const int kw = k.w & (Kseg - 1);
        wave_max4(wt, kx, ky, kz, kw,
                  enc(v.x), enc(v.y), enc(v.z), enc(v.w));
        v = vn;
        k = kn;
    }
    __syncthreads();

    unsigned* dst = part + (size_t)bx * TBLW;
    for (int i = threadIdx.x; i < TBLW; i += TPB) dst[i] = tbl[i];
}

__global__ __launch_bounds__(256) void pool_reduce(
    const unsigned* __restrict__ part, float* __restrict__ out) {
    const int gid = blockIdx.x * 256 + threadIdx.x;  // [0, B*C*K)
    const int k  = gid & (Kseg - 1);
    const int cc = (gid >> 10) & (Cn - 1);
    const int b  = gid >> 16;
    const int cg = cc >> 4, w = cc & (WAVES - 1);

    unsigned acc = ENEG;
    const unsigned* p = part
        + ((size_t)(b * NCGRP + cg) * NCHUNK) * TBLW + w * Kseg + k;
    for (int ch = 0; ch < NCHUNK; ++ch)
        acc = max(acc, p[(size_t)ch * TBLW]);
    out[gid] = dec(acc);
}

// -------- fallback path (ws too small): global atomic merge into d_out -----
__global__ __launch_bounds__(256) void init_enc_k(unsigned* __restrict__ o) {
    o[blockIdx.x * 256 + threadIdx.x] = ENEG;
}

__global__ __launch_bounds__(TPB, 8) void pool_atomic(
    const float* __restrict__ img, const int* __restrict__ spx,
    unsigned* __restrict__ gtab) {
    __shared__ unsigned tbl[TBLW];

    const int bx    = blockIdx.x;
    const int chunk = bx % NCHUNK;
    const int cg    = (bx / NCHUNK) % NCGRP;
    const int b     = bx / (NCHUNK * NCGRP);

    for (int i = threadIdx.x; i < TBLW; i += TPB) tbl[i] = ENEG;
    __syncthreads();

    const int w    = threadIdx.x >> 6;
    const int lane = threadIdx.x & 63;
    unsigned* wt = tbl + w * Kseg;

    const int c = cg * WAVES + w;
    const float* imgc = img + ((size_t)(b * Cn + c)) * HWn
                            + (size_t)chunk * PIX;
    const int*   spxb = spx + (size_t)b * HWn + (size_t)chunk * PIX;

#pragma unroll 4
    for (int it = 0; it < ITERS; ++it) {
        const int q = lane + it * 64;
        const vf4 v = *(const vf4*)(imgc + 4 * q);
        vi4 k = *(const vi4*)(spxb + 4 * q);
        const int kx = k.x & (Kseg - 1);
        const int ky = k.y & (Kseg - 1);
        const int kz = k.z & (Kseg - 1);
        const int kw = k.w & (Kseg - 1);
        wave_max4(wt, kx, ky, kz, kw,
                  enc(v.x), enc(v.y), enc(v.z), enc(v.w));
    }
    __syncthreads();

    // tbl[w*Kseg + k] -> out channel c = cg*WAVES + w
    for (int i = threadIdx.x; i < TBLW; i += TPB) {
        const int k = i & (Kseg - 1), j = i >> 10;
        const unsigned tv = tbl[i];
        unsigned* dst = gtab + (size_t)(b * Cn + cg * WAVES + j) * Kseg + k;
        if (tv > *dst) atomicMax(dst, tv);
    }
}

__global__ __launch_bounds__(256) void decode_inplace(unsigned* __restrict__ o) {
    const int i = blockIdx.x * 256 + threadIdx.x;
    const unsigned e = o[i];
    ((float*)o)[i] = dec(e);
}

extern "C" void kernel_launch(void* const* d_in, const int* in_sizes, int n_in,
                              void* d_out, int out_size, void* d_ws, size_t ws_size,
                              hipStream_t stream) {
    const float* img = (const float*)d_in[0];
    const int*   spx = (const int*)d_in[1];
    float*       out = (float*)d_out;

    const size_t need = (size_t)NBLK * TBLW * sizeof(unsigned);  // 32 MB
    const int nOut256 = (Bn * Cn * Kseg) / 256;                  // 1024

    if (ws_size >= need) {
        unsigned* part = (unsigned*)d_ws;
        pool_partial<<<NBLK, TPB, 0, stream>>>(img, spx, part);
        pool_reduce<<<nOut256, 256, 0, stream>>>(part, out);
    } else {
        unsigned* gt = (unsigned*)d_out;
        init_enc_k<<<nOut256, 256, 0, stream>>>(gt);
        pool_atomic<<<NBLK, TPB, 0, stream>>>(img, spx, gt);
        decode_inplace<<<nOut256, 256, 0, stream>>>(gt);
    }
}